// Round 14
// baseline (388.268 us; speedup 1.0000x reference)
//
#include <hip/hip_runtime.h>

// Viterbi detector, bit-exact vs f32 reference.
// Lane-relabeled trellis: lane l holds state pi_phi(l), phase phi = t&3.
// GF(2)-linear labelings -> ACS partner exchange is a single-DPP pattern
// at EVERY phase: masks (8, 2, 1, 15).
// R14: TWO interleaved chains per consumer wave (A=4 seqs, B=4 seqs).
// Stream per timestep: minA,minB,addA,addB -> each chain's add->min gap
// = 2 instrs = 4cy = VALU latency, DPP hazard covered by 1 intervening
// VALU op (R12-proven). 8cy/timestep for both chains (vs 10cy for one).
// 32 blocks x 5 waves: w0 dual-chain consumer; w1-2 chain-A cost
// producers; w3-4 chain-B (R13 machinery doubled). Raw s_barrier +
// lgkmcnt(0) barriers keep the global_load_lds ring in flight.
// K2 replay: decisions + fused 16-hypothesis traceback -> survivor map +
// 64 path bits/hypothesis. K4 compose. K5 emit = pure-BW bit expansion.

#define DEV static __device__ __forceinline__

static constexpr int T_OUT = 16384;   // output bits per seq
static constexpr int TT    = 16388;   // T + MEM steps
static constexpr int BB    = 256;     // batch
static constexpr int CHUNK = 64;
static constexpr int NFULL = 256;     // full 64-step chunks
static constexpr int NC    = 257;     // + 4-step tail chunk
static constexpr int CROW  = 68;      // cost row stride in floats (16B-aligned)

// inverse labelings, nibble-packed: lane = (IPI_TAB[phi] >> (4*s)) & 15
static constexpr unsigned long long IPI_TAB[4] = {
  0x4b5a6978c3d2e1f0ULL,   // pi_0^-1
  0x4cb35da26e917f80ULL,   // pi_1^-1
  0x46ceb93157dfa820ULL,   // pi_2^-1
  0x4567cdefba983210ULL,   // pi_3^-1
};

DEV int pi_of(int phi, int l){
  int l0=l&1, l1=(l>>1)&1, l2=(l>>2)&1, l3=(l>>3)&1;
  switch(phi & 3){
    case 0:  return (l2)      | ((l2^l0)<<1) | ((l2^l1)<<2) | ((l3^l2)<<3);
    case 1:  return (l3^l2)   | ((l2)<<1)    | ((l2^l0)<<2) | ((l2^l1)<<3);
    case 2:  return (l2^l1)   | ((l3^l2)<<1) | ((l2)<<2)    | ((l2^l0)<<3);
    default: return (l2^l0)   | ((l2^l1)<<1) | ((l3^l2)<<2) | ((l2)<<3);
  }
}

template<int CTRL>
DEV float dppmov(float x){
  return __int_as_float(__builtin_amdgcn_update_dpp(0, __float_as_int(x), CTRL, 0xF, 0xF, true));
}

// partner exchange per phase: masks 8, 2, 1, 15 (all single DPP)
template<int PH>
DEV float partner_of(float p){
  if constexpr (PH == 0) return dppmov<0x128>(p);   // row_ror:8      -> ^8
  else if constexpr (PH == 1) return dppmov<0x4E>(p);    // quad[2,3,0,1] -> ^2
  else if constexpr (PH == 2) return dppmov<0xB1>(p);    // quad[1,0,3,2] -> ^1
  else return dppmov<0x140>(p);                          // row_mirror    -> ^15
}

// expected[s] = sum_j (1-2*bit_j(s)) * h[j], sequential f32 accumulation
DEV float exp_of_state(int s, float h0, float h1, float h2, float h3){
  float e =            ((s     ) & 1) ? -h0 : h0;
  e = __fadd_rn(e, (((s >> 1)) & 1) ? -h1 : h1);
  e = __fadd_rn(e, (((s >> 2)) & 1) ? -h2 : h2);
  e = __fadd_rn(e, (((s >> 3)) & 1) ? -h3 : h3);
  return e;
}

// 4 timesteps of TWO interleaved chains, costs PRE-SQUARED.
// Per timestep: minA,minB,addA,addB. Every DPP src was written >=2 instrs
// earlier (hazard ok); every add->min dep is 2 instrs = 4cy (no stall).
DEV void chain4x2(float& pA, float& pB, const float4 mA, const float4 mB){
  float tA, tB;
  asm volatile(
    "v_min_f32_dpp %2, %0, %0 row_ror:8 row_mask:0xf bank_mask:0xf\n\t"
    "v_min_f32_dpp %3, %1, %1 row_ror:8 row_mask:0xf bank_mask:0xf\n\t"
    "v_add_f32 %0, %2, %4\n\t"
    "v_add_f32 %1, %3, %8\n\t"
    "v_min_f32_dpp %2, %0, %0 quad_perm:[2,3,0,1] row_mask:0xf bank_mask:0xf\n\t"
    "v_min_f32_dpp %3, %1, %1 quad_perm:[2,3,0,1] row_mask:0xf bank_mask:0xf\n\t"
    "v_add_f32 %0, %2, %5\n\t"
    "v_add_f32 %1, %3, %9\n\t"
    "v_min_f32_dpp %2, %0, %0 quad_perm:[1,0,3,2] row_mask:0xf bank_mask:0xf\n\t"
    "v_min_f32_dpp %3, %1, %1 quad_perm:[1,0,3,2] row_mask:0xf bank_mask:0xf\n\t"
    "v_add_f32 %0, %2, %6\n\t"
    "v_add_f32 %1, %3, %10\n\t"
    "v_min_f32_dpp %2, %0, %0 row_mirror row_mask:0xf bank_mask:0xf\n\t"
    "v_min_f32_dpp %3, %1, %1 row_mirror row_mask:0xf bank_mask:0xf\n\t"
    "v_add_f32 %0, %2, %7\n\t"
    "v_add_f32 %1, %3, %11"
    : "+v"(pA), "+v"(pB), "=&v"(tA), "=&v"(tB)
    : "v"(mA.x), "v"(mA.y), "v"(mA.z), "v"(mA.w),
      "v"(mB.x), "v"(mB.y), "v"(mB.z), "v"(mB.w));
}

// async global->LDS, 16B per lane; no destination VGPRs, tracked by vmcnt.
DEV void gload_lds16(const float* g, float* l){
  __builtin_amdgcn_global_load_lds(
      (const __attribute__((address_space(1))) void*)(g),
      (__attribute__((address_space(3))) void*)(l), 16, 0, 0);
}

// raw barrier: LDS visibility only (lgkmcnt), vmcnt stays in flight.
DEV void wg_barrier(){
  asm volatile("s_waitcnt lgkmcnt(0)" ::: "memory");
  __builtin_amdgcn_s_barrier();
}

// ---------------- K1: serial forward (5 waves: 1 dual-chain + 4 cost) ------
__global__ __launch_bounds__(320, 1) void k_forward(const float* __restrict__ y,
                                                    const float* __restrict__ h,
                                                    float* __restrict__ ckpt){
  __shared__ float ringA[8][256];         //  8 KB: y staging, seqs 0-3
  __shared__ float ringB[8][256];         //  8 KB: y staging, seqs 4-7
  __shared__ float costA[2][64 * CROW];   // 34 KB: pre-squared costs A, dbuf
  __shared__ float costB[2][64 * CROW];   // 34 KB: pre-squared costs B, dbuf
  __shared__ float cks[64 * 128];         // 32 KB: ckpt segment [ch][8seq][16]

  const int tid  = threadIdx.x;
  const int wv   = tid >> 6;
  const int lane = tid & 63;

  if (wv == 0){
    // ================= consumer: two interleaved serial chains =============
    const int l16 = lane & 15, s4 = lane >> 4;
    const int st0 = pi_of(0, l16);
    const int row = l16 * 4 + s4;

    float4 qa[16], qb[16], ra[16], rb[16];
    float pA = 0.0f, pB = 0.0f;           // in0 = zeros

    wg_barrier();                         // B0: rings primed
    wg_barrier();                         // B1: buf0 (chunk 0) ready
    {
      const float* ca = &costA[0][0];
      const float* cb = &costB[0][0];
      #pragma unroll
      for (int g = 0; g < 16; ++g) qa[g] = *(const float4*)(ca + row * CROW + 4 * g);
      #pragma unroll
      for (int g = 0; g < 16; ++g) qb[g] = *(const float4*)(cb + row * CROW + 4 * g);
    }
    wg_barrier();                         // B2: buf1 (chunk 1) ready

    for (int k = 0; k < NFULL; k += 2){
      { // period k: consume qa/qb (chunk k), prefetch ra/rb <- buf1 (chunk k+1)
        const float* ca = &costA[1][0];
        const float* cb = &costB[1][0];
        #pragma unroll
        for (int g = 0; g < 16; ++g) ra[g] = *(const float4*)(ca + row * CROW + 4 * g);
        #pragma unroll
        for (int g = 0; g < 16; ++g) rb[g] = *(const float4*)(cb + row * CROW + 4 * g);
        __builtin_amdgcn_sched_barrier(0);
        #pragma unroll
        for (int g = 0; g < 16; ++g)
          chain4x2(pA, pB, qa[g], qb[g]);
        cks[(k & 63) * 128 +      s4 * 16 + st0] = pA;
        cks[(k & 63) * 128 + 64 + s4 * 16 + st0] = pB;
      }
      wg_barrier();
      { // period k+1: consume ra/rb (chunk k+1), prefetch qa/qb <- buf0 (chunk k+2)
        const float* ca = &costA[0][0];
        const float* cb = &costB[0][0];
        #pragma unroll
        for (int g = 0; g < 16; ++g) qa[g] = *(const float4*)(ca + row * CROW + 4 * g);
        #pragma unroll
        for (int g = 0; g < 16; ++g) qb[g] = *(const float4*)(cb + row * CROW + 4 * g);
        __builtin_amdgcn_sched_barrier(0);
        #pragma unroll
        for (int g = 0; g < 16; ++g)
          chain4x2(pA, pB, ra[g], rb[g]);
        cks[((k + 1) & 63) * 128 +      s4 * 16 + st0] = pA;
        cks[((k + 1) & 63) * 128 + 64 + s4 * 16 + st0] = pB;
        if (((k + 1) & 63) == 63){
          const int seg = (k + 1) >> 6;
          #pragma unroll 8
          for (int ch = 0; ch < 64; ++ch){
            const size_t chunkIdx = (size_t)seg * 64 + ch;
            float* dst = ckpt + (chunkIdx * BB + blockIdx.x * 8) * 16;
            dst[lane]      = cks[ch * 128 + lane];
            dst[64 + lane] = cks[ch * 128 + 64 + lane];
          }
          asm volatile("s_waitcnt vmcnt(0)" ::: "memory");  // w0's own stores only
        }
      }
      wg_barrier();
    }
  } else {
    // ================= producers: costs 2 chunks ahead =================
    const bool isA   = (wv <= 2);
    const int  pw    = isA ? (wv - 1) : (wv - 3);   // 0 or 1 within its chain
    const int  gbase = pw * 8;
    float* ring0 = isA ? &ringA[0][0] : &ringB[0][0];
    float* cost0 = isA ? &costA[0][0] : &costB[0][0];
    float* cost1 = isA ? &costA[1][0] : &costB[1][0];
    const bool stager = (pw == 0);

    const int pl16 = lane >> 2;           // state-group of this cost row
    const int ps4  = lane & 3;            // seq-in-chain of this cost row
    const float h0 = h[0], h1 = h[1], h2 = h[2], h3 = h[3];
    const float EA = exp_of_state(pi_of(1,pl16), h0,h1,h2,h3);
    const float EB = exp_of_state(pi_of(2,pl16), h0,h1,h2,h3);
    const float EC = exp_of_state(pi_of(3,pl16), h0,h1,h2,h3);
    const float ED = exp_of_state(pi_of(0,pl16), h0,h1,h2,h3);
    // staging role (stager wave): lane sources seq (lane&3) of its chain
    const float* ysrc = y + (size_t)(blockIdx.x * 8 + (isA ? 0 : 4) + ps4) * TT
                          + pl16 * 4;

    #define PRODUCE(RB, CB)                                                   \
      {                                                                       \
        const float* rb_ = (RB);                                              \
        float* cb_ = (CB);                                                    \
        _Pragma("unroll")                                                     \
        for (int g2 = 0; g2 < 8; ++g2){                                       \
          const int g = gbase + g2;                                           \
          float4 yv = *(const float4*)(rb_ + g * 16 + ps4 * 4);               \
          float4 c; float d;                                                  \
          d = __fsub_rn(yv.x, EA); c.x = __fmul_rn(d, d);                     \
          d = __fsub_rn(yv.y, EB); c.y = __fmul_rn(d, d);                     \
          d = __fsub_rn(yv.z, EC); c.z = __fmul_rn(d, d);                     \
          d = __fsub_rn(yv.w, ED); c.w = __fmul_rn(d, d);                     \
          *(float4*)(cb_ + lane * CROW + 4 * g) = c;                          \
        }                                                                     \
      }

    if (stager){
      #pragma unroll
      for (int q = 0; q < 8; ++q)
        gload_lds16(ysrc + q * CHUNK, ring0 + q * 256);
      asm volatile("s_waitcnt vmcnt(6)" ::: "memory");  // chunks 0,1 landed
    }
    wg_barrier();                         // B0
    PRODUCE(ring0 + 0 * 256, cost0);      // costs chunk 0
    wg_barrier();                         // B1
    PRODUCE(ring0 + 1 * 256, cost1);      // costs chunk 1
    if (stager){
      gload_lds16(ysrc + 8 * CHUNK, ring0 + 0 * 256);
      asm volatile("s_waitcnt vmcnt(6)" ::: "memory");  // chunk 2 landed
    }
    wg_barrier();                         // B2

    for (int k = 0; k < NFULL; k += 2){
      if (k + 2 < NFULL) PRODUCE(ring0 + ((k + 2) & 7) * 256, cost0);
      if (stager){
        const int ci = (k + 9 < NFULL) ? k + 9 : NFULL - 1;
        gload_lds16(ysrc + ci * CHUNK, ring0 + ((k + 9) & 7) * 256);
        asm volatile("s_waitcnt vmcnt(6)" ::: "memory");
      }
      wg_barrier();
      if (k + 3 < NFULL) PRODUCE(ring0 + ((k + 3) & 7) * 256, cost1);
      if (stager){
        const int ci = (k + 10 < NFULL) ? k + 10 : NFULL - 1;
        gload_lds16(ysrc + ci * CHUNK, ring0 + ((k + 10) & 7) * 256);
        asm volatile("s_waitcnt vmcnt(6)" ::: "memory");
      }
      wg_barrier();
    }
    #undef PRODUCE
  }
}

// ---------------- K2: replay -> traceback maps + per-hypothesis path bits ----
// role = (in-state bit3) per phase; decision d = strict (cand_b1 < cand_b0).
template<int PH>
DEV unsigned rstep(float& p, float yv, float E, bool role){
  float partner = partner_of<PH>(p);
  float c1 = role ? p : partner;
  float c0 = role ? partner : p;
  unsigned d = (c1 < c0) ? 1u : 0u;
  float mn = fminf(p, partner);
  float dd = __fsub_rn(yv, E);
  p = __fadd_rn(mn, __fmul_rn(dd, dd));
  return d;
}

__global__ __launch_bounds__(256) void k_replay(const float* __restrict__ y,
                                                const float* __restrict__ h,
                                                const float* __restrict__ ckpt,
                                                unsigned long long* __restrict__ bits,
                                                unsigned char* __restrict__ map){
  const int gt   = blockIdx.x * 256 + threadIdx.x;
  const int pair = gt >> 4;              // c*256 + seq
  const int l16  = gt & 15;
  const int c    = pair >> 8;
  const int seq  = pair & 255;
  const float h0 = h[0], h1 = h[1], h2 = h[2], h3 = h[3];
  const float EA = exp_of_state(pi_of(1,l16), h0,h1,h2,h3);
  const float EB = exp_of_state(pi_of(2,l16), h0,h1,h2,h3);
  const float EC = exp_of_state(pi_of(3,l16), h0,h1,h2,h3);
  const float ED = exp_of_state(pi_of(0,l16), h0,h1,h2,h3);
  const bool r0 = (((l16>>3) ^ (l16>>2)) & 1) != 0;   // bit3 of pi_0(l)
  const bool r1 = (((l16>>2) ^ (l16>>1)) & 1) != 0;   // bit3 of pi_1(l)
  const bool r2 = (((l16>>2) ^  l16    ) & 1) != 0;   // bit3 of pi_2(l)
  const bool r3 = (( l16>>2)             & 1) != 0;   // bit3 of pi_3(l)
  const int  st0 = pi_of(0, l16);

  float p = (c == 0) ? 0.0f : ckpt[((size_t)(c - 1) * BB + seq) * 16 + st0];
  const float* yc = y + (size_t)seq * TT + c * CHUNK;
  unsigned lo = 0, hi = 0;

  if (c < NFULL){
    #pragma unroll
    for (int g = 0; g < 16; ++g){
      float4 yv = *(const float4*)(yc + 4*g);
      unsigned d0 = rstep<0>(p, yv.x, EA, r0);
      unsigned d1 = rstep<1>(p, yv.y, EB, r1);
      unsigned d2 = rstep<2>(p, yv.z, EC, r2);
      unsigned d3 = rstep<3>(p, yv.w, ED, r3);
      const int t = 4 * g;
      if (t < 32) lo |= (d0 << t) | (d1 << (t+1)) | (d2 << (t+2)) | (d3 << (t+3));
      else        hi |= (d0 << (t-32)) | (d1 << (t-31)) | (d2 << (t-30)) | (d3 << (t-29));
    }
  } else {
    float4 yv = *(const float4*)(yc);
    unsigned d0 = rstep<0>(p, yv.x, EA, r0);
    unsigned d1 = rstep<1>(p, yv.y, EB, r1);
    unsigned d2 = rstep<2>(p, yv.z, EC, r2);
    unsigned d3 = rstep<3>(p, yv.w, ED, r3);
    lo = d0 | (d1 << 1) | (d2 << 2) | (d3 << 3);
  }

  // ---- fused traceback: decision words live in this 16-lane group's regs.
  const int base = (threadIdx.x & 63) & 48;
  int s = l16;
  unsigned long long pb = 0ull;
  if (c < NFULL){
    #pragma unroll
    for (int j = 63; j >= 0; --j){
      int l = (int)((IPI_TAB[(j + 1) & 3] >> (4 * s)) & 15);
      unsigned hw = __shfl((j >= 32) ? hi : lo, base + l);
      unsigned long long b = (hw >> (j & 31)) & 1;
      s = (s >> 1) | ((int)b << 3);
      pb |= b << j;
    }
  } else {
    #pragma unroll
    for (int j = 3; j >= 0; --j){
      int l = (int)((IPI_TAB[(j + 1) & 3] >> (4 * s)) & 15);
      unsigned hw = __shfl(lo, base + l);
      unsigned long long b = (hw >> j) & 1;
      s = (s >> 1) | ((int)b << 3);
      pb |= b << j;
    }
  }
  bits[(size_t)pair * 16 + l16] = pb;
  map [(size_t)pair * 16 + l16] = (unsigned char)s;
}

// ---------------- K4: compose maps backward -> chunk end states ----------------
__global__ __launch_bounds__(256) void k_compose(const unsigned char* __restrict__ map,
                                                 unsigned char* __restrict__ Earr){
  const int seq = threadIdx.x;
  int s = 0;
  Earr[(size_t)NFULL * BB + seq] = 0;              // end state of tail chunk = 0
  #pragma unroll 8
  for (int c = NC - 1; c >= 1; --c){
    const uint4 mr = *(const uint4*)(map + ((size_t)c * BB + seq) * 16);
    unsigned wsel = (s < 8) ? ((s < 4) ? mr.x : mr.y) : ((s < 12) ? mr.z : mr.w);
    s = (wsel >> ((s & 3) * 8)) & 15;
    Earr[(size_t)(c - 1) * BB + seq] = (unsigned char)s;
  }
}

// ---------------- K5: emit = select hypothesis, expand bits to floats --------
__global__ __launch_bounds__(256) void k_emit(const unsigned long long* __restrict__ bits,
                                              const unsigned char* __restrict__ Earr,
                                              float* __restrict__ out){
  const int gt   = blockIdx.x * 256 + threadIdx.x;
  const int pair = gt >> 4;        // c*256+seq, c < 256
  const int l16  = gt & 15;
  const int c    = pair >> 8;
  const int seq  = pair & 255;
  const int e    = Earr[(size_t)c * BB + seq];             // broadcast in group
  const unsigned long long w = bits[(size_t)pair * 16 + e];// broadcast in group
  const int j0 = l16 * 4;
  float4 f;
  f.x = (float)((w >> (j0    )) & 1);
  f.y = (float)((w >> (j0 + 1)) & 1);
  f.z = (float)((w >> (j0 + 2)) & 1);
  f.w = (float)((w >> (j0 + 3)) & 1);
  *(float4*)(out + (size_t)seq * T_OUT + c * CHUNK + j0) = f;
}

extern "C" void kernel_launch(void* const* d_in, const int* in_sizes, int n_in,
                              void* d_out, int out_size, void* d_ws, size_t ws_size,
                              hipStream_t stream){
  const float* y = (const float*)d_in[0];
  const float* h = (const float*)d_in[1];
  float* out = (float*)d_out;

  const size_t CKPT_B = (size_t)NFULL * BB * 16 * 4;        // 4,194,304
  const size_t BITS_B = (size_t)NC * BB * 16 * 8;           // 8,421,376
  const size_t MAP_B  = (size_t)NC * BB * 16;               // 1,052,672
  const size_t E_B    = (size_t)NC * BB;                    //    65,792
  if (ws_size < CKPT_B + BITS_B + MAP_B + E_B) return;

  char* ws = (char*)d_ws;
  float*              ckpt = (float*)ws;
  unsigned long long* bits = (unsigned long long*)(ws + CKPT_B);
  unsigned char*      map  = (unsigned char*)(ws + CKPT_B + BITS_B);
  unsigned char*      Earr = (unsigned char*)(ws + CKPT_B + BITS_B + MAP_B);

  hipLaunchKernelGGL(k_forward, dim3(32),   dim3(320), 0, stream, y, h, ckpt);
  hipLaunchKernelGGL(k_replay,  dim3(4112), dim3(256), 0, stream, y, h, ckpt, bits, map);
  hipLaunchKernelGGL(k_compose, dim3(1),    dim3(256), 0, stream, map, Earr);
  hipLaunchKernelGGL(k_emit,    dim3(4096), dim3(256), 0, stream, bits, Earr, out);
}